// Round 1
// baseline (73.081 us; speedup 1.0000x reference)
//
#include <hip/hip_runtime.h>
#include <math.h>

#define ALPHA_C 0.25f
#define TEMPORAL_W 0.8f
#define EPS_C 1e-8f

__device__ __forceinline__ float elem_loss(float x, int t) {
    const float tf = (float)t;
    const float ax = fabsf(x);
    const float e  = expf(-ax);              // exp(-|x|)
    // stable BCE-with-logits: max(x,0) - x*t + log1p(exp(-|x|))
    const float bce = fmaxf(x, 0.0f) - x * tf + log1pf(e);
    // sigmoid via the same exp: x>=0 -> 1/(1+e), x<0 -> e/(1+e)
    const float inv = 1.0f / (1.0f + e);
    const float p   = (x >= 0.0f) ? inv : e * inv;
    const float pt  = t ? p : (1.0f - p);
    const float om  = 1.0f - pt;
    const float focal = -ALPHA_C * om * om * logf(pt + EPS_C);
    return 0.5f * bce + 0.5f * focal;
}

__global__ __launch_bounds__(256) void loss_partial_kernel(
        const float* __restrict__ x, const int* __restrict__ tg,
        float* __restrict__ partial, int n4, int n) {
    const int tid    = blockIdx.x * blockDim.x + threadIdx.x;
    const int stride = gridDim.x * blockDim.x;
    float sum = 0.0f;

    for (int i = tid; i < n4; i += stride) {
        const float4 xv = reinterpret_cast<const float4*>(x)[i];
        const int4   tv = reinterpret_cast<const int4*>(tg)[i];
        // previous 5 targets: indices 4i-1 .. 4i-5 (clamped at array start)
        int p1 = 0, p2 = 0, p3 = 0, p4 = 0, p5 = 0;
        if (i > 0) {
            const int4 pv = reinterpret_cast<const int4*>(tg)[i - 1];
            p1 = pv.w; p2 = pv.z; p3 = pv.y; p4 = pv.x;
            if (i >= 2) p5 = tg[4 * i - 5];
        }
        // "any positive in previous-5 window" per lane (targets are 0/1 -> OR)
        const int w0 = p1 | p2 | p3 | p4 | p5;
        const int w1 = tv.x | p1 | p2 | p3 | p4;
        const int w2 = tv.y | tv.x | p1 | p2 | p3;
        const int w3 = tv.z | tv.y | tv.x | p1 | p2;

        float c0 = elem_loss(xv.x, tv.x);
        float c1 = elem_loss(xv.y, tv.y);
        float c2 = elem_loss(xv.z, tv.z);
        float c3 = elem_loss(xv.w, tv.w);
        c0 *= (tv.x & w0) ? TEMPORAL_W : 1.0f;
        c1 *= (tv.y & w1) ? TEMPORAL_W : 1.0f;
        c2 *= (tv.z & w2) ? TEMPORAL_W : 1.0f;
        c3 *= (tv.w & w3) ? TEMPORAL_W : 1.0f;
        sum += (c0 + c1) + (c2 + c3);
    }

    // scalar tail for n not divisible by 4
    for (int g = 4 * n4 + tid; g < n; g += stride) {
        const int t = tg[g];
        int any = 0;
        #pragma unroll
        for (int k = 1; k <= 5; ++k) if (g - k >= 0) any |= tg[g - k];
        float c = elem_loss(x[g], t);
        if (t && any) c *= TEMPORAL_W;
        sum += c;
    }

    // wave (64-lane) reduction, then cross-wave via LDS
    #pragma unroll
    for (int off = 32; off > 0; off >>= 1) sum += __shfl_down(sum, off);
    __shared__ float wsum[4];
    const int lane = threadIdx.x & 63;
    const int wid  = threadIdx.x >> 6;
    if (lane == 0) wsum[wid] = sum;
    __syncthreads();
    if (threadIdx.x == 0)
        partial[blockIdx.x] = (wsum[0] + wsum[1]) + (wsum[2] + wsum[3]);
}

__global__ __launch_bounds__(256) void final_reduce_kernel(
        const float* __restrict__ partial, int nb,
        float* __restrict__ out, float invN) {
    float s = 0.0f;
    for (int i = threadIdx.x; i < nb; i += 256) s += partial[i];
    #pragma unroll
    for (int off = 32; off > 0; off >>= 1) s += __shfl_down(s, off);
    __shared__ float wsum[4];
    const int lane = threadIdx.x & 63;
    const int wid  = threadIdx.x >> 6;
    if (lane == 0) wsum[wid] = s;
    __syncthreads();
    if (threadIdx.x == 0)
        out[0] = ((wsum[0] + wsum[1]) + (wsum[2] + wsum[3])) * invN;
}

extern "C" void kernel_launch(void* const* d_in, const int* in_sizes, int n_in,
                              void* d_out, int out_size, void* d_ws, size_t ws_size,
                              hipStream_t stream) {
    const float* x  = (const float*)d_in[0];
    const int*   tg = (const int*)d_in[1];
    float* out      = (float*)d_out;
    float* partial  = (float*)d_ws;

    const int n  = in_sizes[0];
    const int n4 = n / 4;
    const int NB = 2048;   // memory-bound: cap blocks, grid-stride the rest

    loss_partial_kernel<<<NB, 256, 0, stream>>>(x, tg, partial, n4, n);
    final_reduce_kernel<<<1, 256, 0, stream>>>(partial, NB, out, 1.0f / (float)n);
}

// Round 2
// 29.622 us; speedup vs baseline: 2.4671x; 2.4671x over previous
//
#include <hip/hip_runtime.h>
#include <math.h>

#define TEMPORAL_W 0.8f
#define LOG2E 1.4426950408889634f
#define LN2   0.6931471805599453f

// ~18 VALU inst, 3 hardware transcendentals (v_exp_f32, v_log_f32, v_rcp_f32).
__device__ __forceinline__ float elem_loss(float x, int t) {
    const float a = fabsf(x);
    const float e = __builtin_amdgcn_exp2f(a * -LOG2E);        // exp(-|x|), e in (0,1]
    const float L = LN2 * __builtin_amdgcn_logf(1.0f + e);     // log1p(e); arg in (1,2]
    // BCE-with-logits: max(x,0) - x*t + log1p(exp(-|x|))
    const float bce = fmaxf(x, 0.0f) - (t ? x : 0.0f) + L;
    // pt = sigmoid agrees with target ? 1/(1+e) : e/(1+e); -log(pt) = L or a+L
    const bool agree = (x >= 0.0f) == (t != 0);
    const float r  = __builtin_amdgcn_rcpf(1.0f + e);
    const float pt = agree ? r : e * r;
    const float mlogpt = agree ? L : (a + L);                  // = -log(pt); EPS negligible
    const float om = 1.0f - pt;
    // combined = 0.5*bce + 0.5*(alpha * om^2 * mlogpt), alpha=0.25
    return 0.5f * (bce + 0.25f * om * om * mlogpt);
}

__global__ __launch_bounds__(256) void loss_partial_kernel(
        const float* __restrict__ x, const int* __restrict__ tg,
        float* __restrict__ partial, int n8, int n) {
    const int tid    = blockIdx.x * blockDim.x + threadIdx.x;
    const int stride = gridDim.x * blockDim.x;
    float sum = 0.0f;

    const float4* x4 = reinterpret_cast<const float4*>(x);
    const int4*   t4 = reinterpret_cast<const int4*>(tg);

    for (int i = tid; i < n8; i += stride) {
        // elements e0..e3 = ta, e4..e7 = tb at global base 8*i
        const float4 xa = x4[2 * i];
        const float4 xb = x4[2 * i + 1];
        const int4   ta = t4[2 * i];
        const int4   tb = t4[2 * i + 1];

        int P1 = 0, P2 = 0, P3 = 0, P4 = 0, P5 = 0;  // tg[8i-1..8i-5]
        if (i > 0) {
            const int4 pv = t4[2 * i - 1];
            P1 = pv.w; P2 = pv.z; P3 = pv.y; P4 = pv.x;
            P5 = tg[8 * i - 5];                       // .w of block 2i-2, L1/L2 hit
        }

        // prefix-ORs for the 5-wide causal window (targets are 0/1)
        const int q2 = P1 | P2, q3 = q2 | P3, q4 = q3 | P4;
        const int s1 = ta.x | ta.y, s2 = s1 | ta.z, s3 = s2 | ta.w;
        const int w0 = q4 | P5;
        const int w1 = ta.x | q4;
        const int w2 = s1 | q3;
        const int w3 = s2 | q2;
        const int w4 = s3 | P1;
        const int w5 = tb.x | s3;
        const int w6 = tb.y | tb.x | ta.w | ta.z | ta.y;
        const int w7 = tb.z | tb.y | tb.x | ta.w | ta.z;

        float c0 = elem_loss(xa.x, ta.x);
        float c1 = elem_loss(xa.y, ta.y);
        float c2 = elem_loss(xa.z, ta.z);
        float c3 = elem_loss(xa.w, ta.w);
        float c4 = elem_loss(xb.x, tb.x);
        float c5 = elem_loss(xb.y, tb.y);
        float c6 = elem_loss(xb.z, tb.z);
        float c7 = elem_loss(xb.w, tb.w);

        c0 *= (ta.x & w0) ? TEMPORAL_W : 1.0f;
        c1 *= (ta.y & w1) ? TEMPORAL_W : 1.0f;
        c2 *= (ta.z & w2) ? TEMPORAL_W : 1.0f;
        c3 *= (ta.w & w3) ? TEMPORAL_W : 1.0f;
        c4 *= (tb.x & w4) ? TEMPORAL_W : 1.0f;
        c5 *= (tb.y & w5) ? TEMPORAL_W : 1.0f;
        c6 *= (tb.z & w6) ? TEMPORAL_W : 1.0f;
        c7 *= (tb.w & w7) ? TEMPORAL_W : 1.0f;

        sum += ((c0 + c1) + (c2 + c3)) + ((c4 + c5) + (c6 + c7));
    }

    // scalar tail for n not divisible by 8
    for (int g = 8 * n8 + tid; g < n; g += stride) {
        const int t = tg[g];
        int any = 0;
        #pragma unroll
        for (int k = 1; k <= 5; ++k) if (g - k >= 0) any |= tg[g - k];
        float c = elem_loss(x[g], t);
        if (t && any) c *= TEMPORAL_W;
        sum += c;
    }

    // wave (64-lane) reduction, then cross-wave via LDS
    #pragma unroll
    for (int off = 32; off > 0; off >>= 1) sum += __shfl_down(sum, off);
    __shared__ float wsum[4];
    const int lane = threadIdx.x & 63;
    const int wid  = threadIdx.x >> 6;
    if (lane == 0) wsum[wid] = sum;
    __syncthreads();
    if (threadIdx.x == 0)
        partial[blockIdx.x] = (wsum[0] + wsum[1]) + (wsum[2] + wsum[3]);
}

__global__ __launch_bounds__(256) void final_reduce_kernel(
        const float* __restrict__ partial, int nb,
        float* __restrict__ out, float invN) {
    float s = 0.0f;
    for (int i = threadIdx.x; i < nb; i += 256) s += partial[i];
    #pragma unroll
    for (int off = 32; off > 0; off >>= 1) s += __shfl_down(s, off);
    __shared__ float wsum[4];
    const int lane = threadIdx.x & 63;
    const int wid  = threadIdx.x >> 6;
    if (lane == 0) wsum[wid] = s;
    __syncthreads();
    if (threadIdx.x == 0)
        out[0] = ((wsum[0] + wsum[1]) + (wsum[2] + wsum[3])) * invN;
}

extern "C" void kernel_launch(void* const* d_in, const int* in_sizes, int n_in,
                              void* d_out, int out_size, void* d_ws, size_t ws_size,
                              hipStream_t stream) {
    const float* x  = (const float*)d_in[0];
    const int*   tg = (const int*)d_in[1];
    float* out      = (float*)d_out;
    float* partial  = (float*)d_ws;

    const int n  = in_sizes[0];
    const int n8 = n / 8;
    const int NB = 2048;   // 8 wg/CU on 256 CUs; grid-stride the rest

    loss_partial_kernel<<<NB, 256, 0, stream>>>(x, tg, partial, n8, n);
    final_reduce_kernel<<<1, 256, 0, stream>>>(partial, NB, out, 1.0f / (float)n);
}